// Round 3
// baseline (262.051 us; speedup 1.0000x reference)
//
#include <hip/hip_runtime.h>

// Problem constants (from the reference):
//   BS=1024, NSEQ=32 (==SPO_NSEQ), NUM_BOX=128, NUM_CTX=5, MAXC=4, L = in_sizes[6]/BS
constexpr int kBS   = 1024;
constexpr int kNSEQ = 32;
constexpr int kNBOX = 128;
constexpr int kNCTX = 5;
constexpr int kMAXC = 4;

// Single fused kernel. Key insight (verified in R1): every (it,b) update reads only
// ORIGINAL ent_attn rows (parents are processed in ascending node order, children
// always have larger indices, each parent row is written exactly once), so all
// pairs are independent and out[b,row,:] is either a copy of ent[b,row,:] or the
// one parent-update for that row — computable in a single pass, one store per elem.
__global__ __launch_bounds__(128) void fused_propagate(
    const float* __restrict__ ent,   // (BS, NSEQ, NBOX) f32
    const float* __restrict__ spo,   // (BS, NSEQ, NBOX, NCTX) f32
    const int*   __restrict__ ctx,   // (BS, NSEQ, NBOX, NCTX) i32
    const float* __restrict__ roi,   // (BS, NSEQ, NBOX, NCTX) f32 (0/1)
    const int*   __restrict__ cls,   // (BS, NBOX) i32
    const float* __restrict__ woc,   // (BS, NSEQ, NBOX) f32
    const int*   __restrict__ pidx,  // (L, BS)
    const float* __restrict__ pval,  // (L, BS)
    const int*   __restrict__ cidx,  // (L, BS, MAXC)
    const int*   __restrict__ eidx,  // (L, BS, MAXC)
    const int*   __restrict__ fsamp, // (L, BS)
    const int*   __restrict__ fslot, // (L, BS)
    float* __restrict__ out,         // (BS, NSEQ, NBOX)
    int L)
{
    const int b   = blockIdx.x;
    const int row = blockIdx.y;
    const int k   = threadIdx.x;     // box index 0..127
    const int rb  = (b * kNSEQ + row) * kNBOX + k;

    // Which iteration (if any) has this row as its valid parent? Uniform scalar
    // scan over L entries; each parent appears at most once.
    int it = -1;
    for (int i = 0; i < L; ++i) {
        const int j = i * kBS + b;
        if (pval[j] > 0.0f && pidx[j] == row) { it = i; break; }
    }
    if (it < 0) {                    // not a parent row: plain copy
        out[rb] = ent[rb];
        return;
    }

    const int idx = it * kBS + b;
    const int c0  = cidx[idx * kMAXC];        // only child slot 0 feeds transfer[:,0,:]
    const int e0  = eidx[idx * kMAXC];
    const int fs  = fsamp[idx];
    const int fl  = fslot[idx];
    const int ep  = eidx[(it * kBS + fs) * kMAXC + fl];  // cross-batch edge for upd_cols

    // cls_mask and roi_mask appear squared in the reference; 0/1 -> apply once.
    const int   clsk = cls[b * kNBOX + k];
    const float cm   = (clsk != -1) ? 1.0f : 0.0f;
    const float a    = ent[(b * kNSEQ + c0) * kNBOX + k] * cm;

    const size_t sb = ((size_t)(b * kNSEQ + e0) * kNBOX + k) * kNCTX;
    float part[kNCTX];
    #pragma unroll
    for (int c = 0; c < kNCTX; ++c)
        part[c] = a * spo[sb + c] * roi[sb + c];

    // transfer0[c] = 1e-6 + sum_k part[c][k]  (128-lane reduce: wave shfl + LDS combine)
    #pragma unroll
    for (int off = 32; off >= 1; off >>= 1) {
        #pragma unroll
        for (int c = 0; c < kNCTX; ++c)
            part[c] += __shfl_xor(part[c], off, 64);
    }
    __shared__ float wsum[2][kNCTX];
    __shared__ float wmax[2];
    const int wave = k >> 6;
    if ((k & 63) == 0) {
        #pragma unroll
        for (int c = 0; c < kNCTX; ++c) wsum[wave][c] = part[c];
    }
    __syncthreads();
    float t[kNCTX];
    #pragma unroll
    for (int c = 0; c < kNCTX; ++c) t[c] = wsum[0][c] + wsum[1][c] + 1e-6f;

    // upd_cols[c] = ctx_idx_adjusted[fs, ep, 0, c]; columns are distinct (base + 7c mod 128)
    const int cbase = (fs * kNSEQ + ep) * kNBOX * kNCTX;  // box index 0
    float val = 1e-6f;
    #pragma unroll
    for (int c = 0; c < kNCTX; ++c) {
        if (ctx[cbase + c] == k) val = t[c];
    }

    float upd = ent[rb] + val * woc[rb];

    // norm = max_k |upd|; divide only if > 1
    float m = fabsf(upd);
    #pragma unroll
    for (int off = 32; off >= 1; off >>= 1)
        m = fmaxf(m, __shfl_xor(m, off, 64));
    if ((k & 63) == 0) wmax[wave] = m;
    __syncthreads();
    const float norm = fmaxf(wmax[0], wmax[1]);
    if (norm > 1.0f) upd /= norm;
    if (clsk == -1) upd = -1.0f;
    out[rb] = upd;
}

extern "C" void kernel_launch(void* const* d_in, const int* in_sizes, int n_in,
                              void* d_out, int out_size, void* d_ws, size_t ws_size,
                              hipStream_t stream) {
    const float* ent   = (const float*)d_in[0];
    const float* spo   = (const float*)d_in[1];
    const int*   ctx   = (const int*)  d_in[2];
    const float* roi   = (const float*)d_in[3];
    const int*   cls   = (const int*)  d_in[4];
    const float* woc   = (const float*)d_in[5];
    const int*   pidx  = (const int*)  d_in[6];
    const float* pval  = (const float*)d_in[7];
    const int*   cidx  = (const int*)  d_in[8];
    // d_in[9] = child_valid: when parent_valid==1, child_valid[...,0]==1 always -> unused
    const int*   eidx  = (const int*)  d_in[10];
    const int*   fsamp = (const int*)  d_in[11];
    const int*   fslot = (const int*)  d_in[12];
    float* out = (float*)d_out;

    const int L = in_sizes[6] / kBS;   // depth of the padded traversal

    fused_propagate<<<dim3(kBS, kNSEQ), dim3(128), 0, stream>>>(
        ent, spo, ctx, roi, cls, woc, pidx, pval, cidx, eidx, fsamp, fslot, out, L);
}

// Round 4
// 240.899 us; speedup vs baseline: 1.0878x; 1.0878x over previous
//
#include <hip/hip_runtime.h>

// Problem constants: BS=1024, NSEQ=32, NUM_BOX=128, NUM_CTX=5, MAXC=4, L=in_sizes[6]/BS
constexpr int kBS   = 1024;
constexpr int kNSEQ = 32;
constexpr int kNBOX = 128;
constexpr int kNCTX = 5;
constexpr int kMAXC = 4;

// One block per (batch, row-half). Wave 0 builds the row->iteration table in one
// parallel round (replaces R3's serial L-scan that made every block latency-bound).
// Each wave owns 4 rows; each lane holds boxes k=2*lane and 2*lane+1, so the
// 128-box reductions are pure wave-local shfl_xor — no per-row __syncthreads.
// All (it,b) updates read only ORIGINAL ent rows (parents ascend, children > parent,
// each parent written once) -> fully parallel, one store per output element.
__global__ __launch_bounds__(256) void fused_propagate(
    const float* __restrict__ ent,   // (BS, NSEQ, NBOX) f32
    const float* __restrict__ spo,   // (BS, NSEQ, NBOX, NCTX) f32
    const int*   __restrict__ ctx,   // (BS, NSEQ, NBOX, NCTX) i32
    const float* __restrict__ roi,   // (BS, NSEQ, NBOX, NCTX) f32 (0/1)
    const int*   __restrict__ cls,   // (BS, NBOX) i32
    const float* __restrict__ woc,   // (BS, NSEQ, NBOX) f32
    const int*   __restrict__ pidx,  // (L, BS)
    const float* __restrict__ pval,  // (L, BS)
    const int*   __restrict__ cidx,  // (L, BS, MAXC)
    const int*   __restrict__ eidx,  // (L, BS, MAXC)
    const int*   __restrict__ fsamp, // (L, BS)
    const int*   __restrict__ fslot, // (L, BS)
    float* __restrict__ out,         // (BS, NSEQ, NBOX)
    int L)
{
    const int b    = blockIdx.x;
    const int half = blockIdx.y;          // rows [half*16, half*16+16)
    const int tid  = threadIdx.x;
    const int lane = tid & 63;
    const int wave = tid >> 6;            // 0..3

    __shared__ int rowit[kNSEQ];
    if (wave == 0) {
        if (lane < kNSEQ) rowit[lane] = -1;
        // same wave executes init then scatter in order — no intra-wave race
        for (int i = lane; i < L; i += 64) {
            const int j = i * kBS + b;
            if (pval[j] > 0.0f) rowit[pidx[j]] = i;   // parents are unique
        }
    }
    __syncthreads();

    const int  k0   = 2 * lane, k1 = k0 + 1;
    const int2 clsv = *(const int2*)&cls[b * kNBOX + k0];

    #pragma unroll
    for (int r = 0; r < 4; ++r) {
        const int row = half * 16 + wave * 4 + r;
        const int rb  = (b * kNSEQ + row) * kNBOX;
        const int it  = rowit[row];        // wave-uniform
        if (it < 0) {                      // not a parent row: plain copy
            *(float2*)&out[rb + k0] = *(const float2*)&ent[rb + k0];
            continue;
        }
        const int idx = it * kBS + b;
        const int c0  = cidx[idx * kMAXC];   // only child slot 0 feeds transfer[:,0,:]
        const int e0  = eidx[idx * kMAXC];
        const int fs  = fsamp[idx];
        const int fl  = fslot[idx];
        const int ep  = eidx[(it * kBS + fs) * kMAXC + fl];  // cross-batch edge

        // ch_atn (cls_mask & roi_mask are 0/1 and appear squared -> apply once)
        const float2 av = *(const float2*)&ent[(b * kNSEQ + c0) * kNBOX + k0];
        const float a0 = (clsv.x != -1) ? av.x : 0.0f;
        const float a1 = (clsv.y != -1) ? av.y : 0.0f;

        const size_t sbase = ((size_t)(b * kNSEQ + e0) * kNBOX + k0) * kNCTX;
        float part[kNCTX];
        #pragma unroll
        for (int c = 0; c < kNCTX; ++c)
            part[c] = a0 * spo[sbase + c]         * roi[sbase + c]
                    + a1 * spo[sbase + kNCTX + c] * roi[sbase + kNCTX + c];

        #pragma unroll
        for (int off = 32; off >= 1; off >>= 1) {
            #pragma unroll
            for (int c = 0; c < kNCTX; ++c)
                part[c] += __shfl_xor(part[c], off, 64);
        }

        // upd_cols[c] = ctx[fs, ep, 0, c]; scatter transfer into the row
        const int cbase = (fs * kNSEQ + ep) * kNBOX * kNCTX;
        float val0 = 1e-6f, val1 = 1e-6f;
        #pragma unroll
        for (int c = 0; c < kNCTX; ++c) {
            const int   cc = ctx[cbase + c];
            const float tc = part[c] + 1e-6f;
            if (cc == k0) val0 = tc;
            if (cc == k1) val1 = tc;
        }

        const float2 ev = *(const float2*)&ent[rb + k0];
        const float2 wv = *(const float2*)&woc[rb + k0];
        float u0 = ev.x + val0 * wv.x;
        float u1 = ev.y + val1 * wv.y;

        float m = fmaxf(fabsf(u0), fabsf(u1));
        #pragma unroll
        for (int off = 32; off >= 1; off >>= 1)
            m = fmaxf(m, __shfl_xor(m, off, 64));
        if (m > 1.0f) { u0 /= m; u1 /= m; }
        if (clsv.x == -1) u0 = -1.0f;
        if (clsv.y == -1) u1 = -1.0f;
        *(float2*)&out[rb + k0] = make_float2(u0, u1);
    }
}

extern "C" void kernel_launch(void* const* d_in, const int* in_sizes, int n_in,
                              void* d_out, int out_size, void* d_ws, size_t ws_size,
                              hipStream_t stream) {
    const float* ent   = (const float*)d_in[0];
    const float* spo   = (const float*)d_in[1];
    const int*   ctx   = (const int*)  d_in[2];
    const float* roi   = (const float*)d_in[3];
    const int*   cls   = (const int*)  d_in[4];
    const float* woc   = (const float*)d_in[5];
    const int*   pidx  = (const int*)  d_in[6];
    const float* pval  = (const float*)d_in[7];
    const int*   cidx  = (const int*)  d_in[8];
    // d_in[9] = child_valid: when parent_valid==1, child_valid[...,0]==1 always -> unused
    const int*   eidx  = (const int*)  d_in[10];
    const int*   fsamp = (const int*)  d_in[11];
    const int*   fslot = (const int*)  d_in[12];
    float* out = (float*)d_out;

    const int L = in_sizes[6] / kBS;   // depth of the padded traversal

    fused_propagate<<<dim3(kBS, 2), dim3(256), 0, stream>>>(
        ent, spo, ctx, roi, cls, woc, pidx, pval, cidx, eidx, fsamp, fslot, out, L);
}